// Round 3
// baseline (3685.592 us; speedup 1.0000x reference)
//
#include <hip/hip_runtime.h>
#include <hip/hip_bf16.h>

typedef unsigned short u16;
typedef __attribute__((ext_vector_type(8))) short bf16x8;
typedef __attribute__((ext_vector_type(4))) float f32x4;

#define DEVI __device__ __forceinline__

constexpr float SCALE = 0.125f;   // DH^-0.5, exact power of 2
constexpr float NEGV  = -1e9f;

DEVI float bf2f(u16 u) { unsigned v = ((unsigned)u) << 16; float f; __builtin_memcpy(&f, &v, 4); return f; }
DEVI u16 f2bf(float f) { __hip_bfloat16 h = __float2bfloat16(f); u16 u; __builtin_memcpy(&u, &h, 2); return u; }

// ---------------------------------------------------------------------------
// Cast fp32 -> bf16, 4 elems/thread. n must be divisible by 1024.
// ---------------------------------------------------------------------------
__global__ __launch_bounds__(256) void cast_f32_bf16(const float* __restrict__ in,
                                                     u16* __restrict__ out, int n) {
    int i = (blockIdx.x * 256 + threadIdx.x) * 4;
    if (i >= n) return;
    float4 v = *(const float4*)(in + i);
    ushort4 o;
    o.x = f2bf(v.x); o.y = f2bf(v.y); o.z = f2bf(v.z); o.w = f2bf(v.w);
    *(ushort4*)(out + i) = o;
}

// ---------------------------------------------------------------------------
// Transpose + cast: in fp32 [R][C] -> out bf16 [C][R]. grid = (C/64, R/64).
// ---------------------------------------------------------------------------
__global__ __launch_bounds__(256) void transpose_f32_bf16(const float* __restrict__ in,
                                                          u16* __restrict__ out,
                                                          int R, int C) {
    __shared__ u16 t[64][65];
    int r0 = blockIdx.y * 64, c0 = blockIdx.x * 64;
    int tid = threadIdx.x;
    for (int i = 0; i < 16; i++) {
        int idx = tid + i * 256; int r = idx >> 6, c = idx & 63;
        t[r][c] = f2bf(in[(size_t)(r0 + r) * C + c0 + c]);
    }
    __syncthreads();
    for (int i = 0; i < 16; i++) {
        int idx = tid + i * 256; int c = idx >> 6, r = idx & 63;
        out[(size_t)(c0 + c) * R + r0 + r] = t[r][c];
    }
}

// ---------------------------------------------------------------------------
// GEMM: C[M][N] = A[M][K] @ Bt[N][K]^T (+fp32 bias). A,Bt bf16; C bf16 or f32.
// 128x128 tile, BK=64, 4 waves; LDS rows padded to 72 bf16 (m97-ladder shape).
// ---------------------------------------------------------------------------
template <bool BIAS, bool F32OUT>
__global__ __launch_bounds__(256) void gemm_bt(const u16* __restrict__ A,
                                               const u16* __restrict__ Bt,
                                               const float* __restrict__ bias,
                                               void* __restrict__ Cv,
                                               int M, int N, int K) {
    constexpr int LDT = 72;
    __shared__ alignas(16) u16 As[128 * LDT];
    __shared__ alignas(16) u16 Bs[128 * LDT];
    int tid = threadIdx.x;
    int wave = tid >> 6, lane = tid & 63, quad = lane >> 4, lm = lane & 15;
    int bm = blockIdx.y * 128, bn = blockIdx.x * 128;
    int wm = (wave >> 1) * 64, wn = (wave & 1) * 64;

    f32x4 acc[4][4];
    for (int i = 0; i < 4; i++) for (int j = 0; j < 4; j++) acc[i][j] = f32x4{0.f, 0.f, 0.f, 0.f};

    for (int kb = 0; kb < K; kb += 64) {
        for (int i = 0; i < 4; i++) {
            int c = tid + i * 256; int r = c >> 3, off = c & 7;
            *(bf16x8*)(&As[r * LDT + off * 8]) =
                *(const bf16x8*)(A + (size_t)(bm + r) * K + kb + off * 8);
            *(bf16x8*)(&Bs[r * LDT + off * 8]) =
                *(const bf16x8*)(Bt + (size_t)(bn + r) * K + kb + off * 8);
        }
        __syncthreads();
        for (int ks = 0; ks < 2; ks++) {
            bf16x8 af[4], bfr[4];
            for (int mt = 0; mt < 4; mt++)
                af[mt] = *(const bf16x8*)(&As[(wm + mt * 16 + lm) * LDT + ks * 32 + quad * 8]);
            for (int nt = 0; nt < 4; nt++)
                bfr[nt] = *(const bf16x8*)(&Bs[(wn + nt * 16 + lm) * LDT + ks * 32 + quad * 8]);
            for (int mt = 0; mt < 4; mt++)
                for (int nt = 0; nt < 4; nt++)
                    acc[mt][nt] = __builtin_amdgcn_mfma_f32_16x16x32_bf16(
                        af[mt], bfr[nt], acc[mt][nt], 0, 0, 0);
        }
        __syncthreads();
    }
    for (int mt = 0; mt < 4; mt++)
        for (int nt = 0; nt < 4; nt++) {
            int col = bn + wn + nt * 16 + lm;
            float bv = BIAS ? bias[col] : 0.f;
            for (int r = 0; r < 4; r++) {
                int row = bm + wm + mt * 16 + quad * 4 + r;
                if (F32OUT) ((float*)Cv)[(size_t)row * N + col] = acc[mt][nt][r] + bv;
                else        ((u16*)Cv)[(size_t)row * N + col] = f2bf(acc[mt][nt][r] + bv);
            }
        }
}

// ---------------------------------------------------------------------------
// Naive attention (correctness control): one thread per (b, h, q) row.
// Two sweeps over keys: (1) online max/sum; (2) p -> attn (fp32), O -> o_ws.
// ---------------------------------------------------------------------------
__global__ __launch_bounds__(256) void attn_naive(const u16* __restrict__ qkv,
                                                  const int* __restrict__ mask,
                                                  float* __restrict__ attn_out,
                                                  u16* __restrict__ o_ws) {
    int gid = blockIdx.x * 256 + threadIdx.x;   // 131072 = 128 bh * 1024 q
    int q  = gid & 1023;
    int bh = gid >> 10;
    int b = bh >> 4, h = bh & 15;

    const u16* qrow  = qkv + (size_t)(b * 1024 + q) * 3072 + h * 64;
    const u16* kbase = qkv + (size_t)b * 1024 * 3072 + 1024 + h * 64;
    const u16* vbase = qkv + (size_t)b * 1024 * 3072 + 2048 + h * 64;
    const int* mrow  = mask + b * 1024;

    float qv[64];
    for (int dv = 0; dv < 8; dv++) {
        bf16x8 t = *(const bf16x8*)(qrow + dv * 8);
        for (int j = 0; j < 8; j++) qv[dv * 8 + j] = bf2f((u16)t[j]);
    }

    // ---- pass 1: online max / sum-exp ----
    float m = -1e30f, l = 0.f;
    for (int k = 0; k < 1024; k++) {
        float s;
        if (mrow[k] == 0) {
            s = NEGV;
        } else {
            const u16* kr = kbase + (size_t)k * 3072;
            float acc = 0.f;
            for (int dv = 0; dv < 8; dv++) {
                bf16x8 kv8 = *(const bf16x8*)(kr + dv * 8);
                for (int j = 0; j < 8; j++) acc += qv[dv * 8 + j] * bf2f((u16)kv8[j]);
            }
            s = acc * SCALE;
        }
        float mn = fmaxf(m, s);
        l = l * __expf(m - mn) + __expf(s - mn);
        m = mn;
    }
    float invl = 1.0f / l;

    // ---- pass 2: recompute scores, write P (fp32), accumulate O ----
    float o[64];
    for (int d = 0; d < 64; d++) o[d] = 0.f;
    float* arow = attn_out + ((size_t)bh * 1024 + q) * 1024;
    for (int k = 0; k < 1024; k++) {
        float s;
        if (mrow[k] == 0) {
            s = NEGV;
        } else {
            const u16* kr = kbase + (size_t)k * 3072;
            float acc = 0.f;
            for (int dv = 0; dv < 8; dv++) {
                bf16x8 kv8 = *(const bf16x8*)(kr + dv * 8);
                for (int j = 0; j < 8; j++) acc += qv[dv * 8 + j] * bf2f((u16)kv8[j]);
            }
            s = acc * SCALE;
        }
        float p = __expf(s - m) * invl;
        arow[k] = p;
        const u16* vr = vbase + (size_t)k * 3072;
        for (int dv = 0; dv < 8; dv++) {
            bf16x8 vv8 = *(const bf16x8*)(vr + dv * 8);
            for (int j = 0; j < 8; j++) o[dv * 8 + j] += p * bf2f((u16)vv8[j]);
        }
    }
    u16* orow = o_ws + (size_t)(b * 1024 + q) * 1024 + h * 64;
    for (int d = 0; d < 64; d++) orow[d] = f2bf(o[d]);
}

// ---------------------------------------------------------------------------
extern "C" void kernel_launch(void* const* d_in, const int* in_sizes, int n_in,
                              void* d_out, int out_size, void* d_ws, size_t ws_size,
                              hipStream_t stream) {
    const float* x    = (const float*)d_in[0];   // fp32 per reference
    const int*   mask = (const int*)d_in[1];
    const float* wqkv = (const float*)d_in[2];
    const float* wout = (const float*)d_in[3];
    const float* bout = (const float*)d_in[4];

    float* out  = (float*)d_out;                    // [8192][1024] fp32
    float* attn = out + (size_t)8192 * 1024;        // [128][1024][1024] fp32

    // workspace layout (~92 MB, no aliasing):
    char* ws = (char*)d_ws;
    u16* xbf   = (u16*)(ws);                        // 16,777,216 B
    u16* qkv   = (u16*)(ws + 16777216);             // 50,331,648 B
    u16* o_ws  = (u16*)(ws + 67108864);             // 16,777,216 B
    u16* wqkvT = (u16*)(ws + 83886080);             //  6,291,456 B
    u16* woutT = (u16*)(ws + 90177536);             //  2,097,152 B

    cast_f32_bf16<<<dim3(8192), 256, 0, stream>>>(x, xbf, 8388608);
    transpose_f32_bf16<<<dim3(48, 16), 256, 0, stream>>>(wqkv, wqkvT, 1024, 3072);
    transpose_f32_bf16<<<dim3(16, 16), 256, 0, stream>>>(wout, woutT, 1024, 1024);
    gemm_bt<false, false><<<dim3(24, 64), 256, 0, stream>>>(xbf, wqkvT, nullptr, qkv, 8192, 3072, 1024);
    attn_naive<<<dim3(512), 256, 0, stream>>>(qkv, mask, attn, o_ws);
    gemm_bt<true, true><<<dim3(8, 64), 256, 0, stream>>>(o_ws, woutT, bout, out, 8192, 1024, 1024);
}

// Round 4
// 934.198 us; speedup vs baseline: 3.9452x; 3.9452x over previous
//
#include <hip/hip_runtime.h>
#include <hip/hip_bf16.h>

typedef unsigned short u16;
typedef __attribute__((ext_vector_type(8))) short bf16x8;
typedef __attribute__((ext_vector_type(4))) float f32x4;

#define DEVI __device__ __forceinline__

constexpr float SCALE = 0.125f;   // DH^-0.5, exact power of 2
constexpr float NEGV  = -1e9f;

DEVI float bf2f(u16 u) { unsigned v = ((unsigned)u) << 16; float f; __builtin_memcpy(&f, &v, 4); return f; }
DEVI u16 f2bf(float f) { __hip_bfloat16 h = __float2bfloat16(f); u16 u; __builtin_memcpy(&u, &h, 2); return u; }

// ---------------------------------------------------------------------------
// Cast fp32 -> bf16, 4 elems/thread.
// ---------------------------------------------------------------------------
__global__ __launch_bounds__(256) void cast_f32_bf16(const float* __restrict__ in,
                                                     u16* __restrict__ out, int n) {
    int i = (blockIdx.x * 256 + threadIdx.x) * 4;
    if (i >= n) return;
    float4 v = *(const float4*)(in + i);
    ushort4 o;
    o.x = f2bf(v.x); o.y = f2bf(v.y); o.z = f2bf(v.z); o.w = f2bf(v.w);
    *(ushort4*)(out + i) = o;
}

// ---------------------------------------------------------------------------
// Transpose + cast: in fp32 [R][C] -> out bf16 [C][R]. grid = (C/64, R/64).
// ---------------------------------------------------------------------------
__global__ __launch_bounds__(256) void transpose_f32_bf16(const float* __restrict__ in,
                                                          u16* __restrict__ out,
                                                          int R, int C) {
    __shared__ u16 t[64][65];
    int r0 = blockIdx.y * 64, c0 = blockIdx.x * 64;
    int tid = threadIdx.x;
    for (int i = 0; i < 16; i++) {
        int idx = tid + i * 256; int r = idx >> 6, c = idx & 63;
        t[r][c] = f2bf(in[(size_t)(r0 + r) * C + c0 + c]);
    }
    __syncthreads();
    for (int i = 0; i < 16; i++) {
        int idx = tid + i * 256; int c = idx >> 6, r = idx & 63;
        out[(size_t)(c0 + c) * R + r0 + r] = t[r][c];
    }
}

// ---------------------------------------------------------------------------
// Vt: qkv V-part [b,n,h,dh] -> vt[bh][dh][n].  grid = (16 n-tiles, 128 bh).
// ---------------------------------------------------------------------------
__global__ __launch_bounds__(256) void make_vt(const u16* __restrict__ qkv,
                                               u16* __restrict__ vt) {
    __shared__ u16 t[64][65];
    int bh = blockIdx.y; int b = bh >> 4, h = bh & 15;
    int n0 = blockIdx.x * 64;
    int tid = threadIdx.x;
    const u16* src = qkv + (size_t)b * 1024 * 3072 + 2048 + h * 64;
    for (int i = 0; i < 16; i++) {
        int idx = tid + i * 256; int n = idx >> 6, d = idx & 63;
        t[n][d] = src[(size_t)(n0 + n) * 3072 + d];
    }
    __syncthreads();
    u16* dst = vt + (size_t)bh * 64 * 1024;
    for (int i = 0; i < 16; i++) {
        int idx = tid + i * 256; int d = idx >> 6, n = idx & 63;
        dst[(size_t)d * 1024 + n0 + n] = t[n][d];
    }
}

// ---------------------------------------------------------------------------
// GEMM: C[M][N] = A[M][K] @ Bt[N][K]^T (+fp32 bias). A,Bt bf16; C bf16 or f32.
// 128x128 tile, BK=64, 4 waves; LDS rows padded to 72 bf16.
// ---------------------------------------------------------------------------
template <bool BIAS, bool F32OUT>
__global__ __launch_bounds__(256) void gemm_bt(const u16* __restrict__ A,
                                               const u16* __restrict__ Bt,
                                               const float* __restrict__ bias,
                                               void* __restrict__ Cv,
                                               int M, int N, int K) {
    constexpr int LDT = 72;
    __shared__ alignas(16) u16 As[128 * LDT];
    __shared__ alignas(16) u16 Bs[128 * LDT];
    int tid = threadIdx.x;
    int wave = tid >> 6, lane = tid & 63, quad = lane >> 4, lm = lane & 15;
    int bm = blockIdx.y * 128, bn = blockIdx.x * 128;
    int wm = (wave >> 1) * 64, wn = (wave & 1) * 64;

    f32x4 acc[4][4];
    for (int i = 0; i < 4; i++) for (int j = 0; j < 4; j++) acc[i][j] = f32x4{0.f, 0.f, 0.f, 0.f};

    for (int kb = 0; kb < K; kb += 64) {
        for (int i = 0; i < 4; i++) {
            int c = tid + i * 256; int r = c >> 3, off = c & 7;
            *(bf16x8*)(&As[r * LDT + off * 8]) =
                *(const bf16x8*)(A + (size_t)(bm + r) * K + kb + off * 8);
            *(bf16x8*)(&Bs[r * LDT + off * 8]) =
                *(const bf16x8*)(Bt + (size_t)(bn + r) * K + kb + off * 8);
        }
        __syncthreads();
        for (int ks = 0; ks < 2; ks++) {
            bf16x8 af[4], bfr[4];
            for (int mt = 0; mt < 4; mt++)
                af[mt] = *(const bf16x8*)(&As[(wm + mt * 16 + lm) * LDT + ks * 32 + quad * 8]);
            for (int nt = 0; nt < 4; nt++)
                bfr[nt] = *(const bf16x8*)(&Bs[(wn + nt * 16 + lm) * LDT + ks * 32 + quad * 8]);
            for (int mt = 0; mt < 4; mt++)
                for (int nt = 0; nt < 4; nt++)
                    acc[mt][nt] = __builtin_amdgcn_mfma_f32_16x16x32_bf16(
                        af[mt], bfr[nt], acc[mt][nt], 0, 0, 0);
        }
        __syncthreads();
    }
    for (int mt = 0; mt < 4; mt++)
        for (int nt = 0; nt < 4; nt++) {
            int col = bn + wn + nt * 16 + lm;
            float bv = BIAS ? bias[col] : 0.f;
            for (int r = 0; r < 4; r++) {
                int row = bm + wm + mt * 16 + quad * 4 + r;
                if (F32OUT) ((float*)Cv)[(size_t)row * N + col] = acc[mt][nt][r] + bv;
                else        ((u16*)Cv)[(size_t)row * N + col] = f2bf(acc[mt][nt][r] + bv);
            }
        }
}

// ---------------------------------------------------------------------------
// MFMA attention: grid = (16 q-blocks, 128 bh), 256 thr (4 waves x 16 q-rows).
// Sweep 1: online row max/sum over 16 key-tiles. Sweep 2: recompute scores,
// write P fp32 (from regs) to attn, P bf16 to LDS, O += P.V via MFMA.
// ---------------------------------------------------------------------------
__global__ __launch_bounds__(256) void attn_mfma(const u16* __restrict__ qkv,
                                                 const u16* __restrict__ vt,
                                                 const int* __restrict__ mask,
                                                 float* __restrict__ attn_out,
                                                 u16* __restrict__ o_ws) {
    constexpr int LDT = 72;
    __shared__ alignas(16) u16 Ks[64 * LDT];
    __shared__ alignas(16) u16 Vs[64 * LDT];
    __shared__ alignas(16) u16 Ps[64 * LDT];

    int tid = threadIdx.x;
    int wave = tid >> 6, lane = tid & 63, quad = lane >> 4, lm = lane & 15;
    int bh = blockIdx.y; int b = bh >> 4, h = bh & 15;
    int qb = blockIdx.x;
    int qrow0 = qb * 64 + wave * 16;

    // Q fragments for this wave's 16 rows (held in regs for whole kernel)
    bf16x8 qf[2];
    {
        const u16* qptr = qkv + (size_t)(b * 1024 + qrow0 + lm) * 3072 + h * 64 + quad * 8;
        qf[0] = *(const bf16x8*)(qptr);
        qf[1] = *(const bf16x8*)(qptr + 32);
    }
    const u16* kbase  = qkv + (size_t)b * 1024 * 3072 + 1024 + h * 64;
    const u16* vtbase = vt + (size_t)bh * 64 * 1024;
    const int* mrow   = mask + b * 1024;

    float m_r[4], l_r[4];
    for (int r = 0; r < 4; r++) { m_r[r] = -1e30f; l_r[r] = 0.f; }

    // ---- sweep 1: row max + sum-exp (online) ----
    for (int kb = 0; kb < 16; kb++) {
        for (int i = 0; i < 2; i++) {
            int c = tid + i * 256; int r = c >> 3, off = c & 7;
            *(bf16x8*)(&Ks[r * LDT + off * 8]) =
                *(const bf16x8*)(kbase + (size_t)(kb * 64 + r) * 3072 + off * 8);
        }
        __syncthreads();
        f32x4 acc[4];
        for (int nt = 0; nt < 4; nt++) acc[nt] = f32x4{0.f, 0.f, 0.f, 0.f};
        for (int ks = 0; ks < 2; ks++)
            for (int nt = 0; nt < 4; nt++) {
                bf16x8 kf = *(const bf16x8*)(&Ks[(nt * 16 + lm) * LDT + ks * 32 + quad * 8]);
                acc[nt] = __builtin_amdgcn_mfma_f32_16x16x32_bf16(qf[ks], kf, acc[nt], 0, 0, 0);
            }
        bool mk[4];
        for (int nt = 0; nt < 4; nt++) mk[nt] = (mrow[kb * 64 + nt * 16 + lm] != 0);
        float sv[4][4];
        for (int nt = 0; nt < 4; nt++)
            for (int r = 0; r < 4; r++)
                sv[nt][r] = mk[nt] ? acc[nt][r] * SCALE : NEGV;
        for (int r = 0; r < 4; r++) {
            float mx = fmaxf(fmaxf(sv[0][r], sv[1][r]), fmaxf(sv[2][r], sv[3][r]));
            for (int s = 8; s >= 1; s >>= 1) mx = fmaxf(mx, __shfl_xor(mx, s, 64));
            float sm = 0.f;
            for (int nt = 0; nt < 4; nt++) sm += __expf(sv[nt][r] - mx);
            for (int s = 8; s >= 1; s >>= 1) sm += __shfl_xor(sm, s, 64);
            float mo = m_r[r], mn = fmaxf(mo, mx);
            l_r[r] = l_r[r] * __expf(mo - mn) + sm * __expf(mx - mn);
            m_r[r] = mn;
        }
        __syncthreads();
    }
    float invl[4];
    for (int r = 0; r < 4; r++) invl[r] = 1.0f / l_r[r];

    // ---- sweep 2: P -> global fp32 + LDS bf16, O += P.V ----
    f32x4 oacc[4];
    for (int nt = 0; nt < 4; nt++) oacc[nt] = f32x4{0.f, 0.f, 0.f, 0.f};
    for (int kb = 0; kb < 16; kb++) {
        for (int i = 0; i < 2; i++) {
            int c = tid + i * 256; int r = c >> 3, off = c & 7;
            *(bf16x8*)(&Ks[r * LDT + off * 8]) =
                *(const bf16x8*)(kbase + (size_t)(kb * 64 + r) * 3072 + off * 8);
            *(bf16x8*)(&Vs[r * LDT + off * 8]) =
                *(const bf16x8*)(vtbase + (size_t)r * 1024 + kb * 64 + off * 8);
        }
        __syncthreads();
        f32x4 acc[4];
        for (int nt = 0; nt < 4; nt++) acc[nt] = f32x4{0.f, 0.f, 0.f, 0.f};
        for (int ks = 0; ks < 2; ks++)
            for (int nt = 0; nt < 4; nt++) {
                bf16x8 kf = *(const bf16x8*)(&Ks[(nt * 16 + lm) * LDT + ks * 32 + quad * 8]);
                acc[nt] = __builtin_amdgcn_mfma_f32_16x16x32_bf16(qf[ks], kf, acc[nt], 0, 0, 0);
            }
        for (int nt = 0; nt < 4; nt++) {
            bool mk = (mrow[kb * 64 + nt * 16 + lm] != 0);
            for (int r = 0; r < 4; r++) {
                float s = mk ? acc[nt][r] * SCALE : NEGV;
                float p = __expf(s - m_r[r]) * invl[r];
                // fp32 attn write, coalesced 64B segments across lm
                attn_out[((size_t)bh * 1024 + qb * 64 + wave * 16 + quad * 4 + r) * 1024
                         + kb * 64 + nt * 16 + lm] = p;
                Ps[(wave * 16 + quad * 4 + r) * LDT + nt * 16 + lm] = f2bf(p);
            }
        }
        __syncthreads();   // Ps visible (cross-lane ordering insurance)
        // O += P.V
        for (int ks = 0; ks < 2; ks++) {
            bf16x8 pf = *(const bf16x8*)(&Ps[(wave * 16 + lm) * LDT + ks * 32 + quad * 8]);
            for (int nt = 0; nt < 4; nt++) {
                bf16x8 vf = *(const bf16x8*)(&Vs[(nt * 16 + lm) * LDT + ks * 32 + quad * 8]);
                oacc[nt] = __builtin_amdgcn_mfma_f32_16x16x32_bf16(pf, vf, oacc[nt], 0, 0, 0);
            }
        }
        __syncthreads();
    }
    // O -> ws as [b, n, h*dh]
    for (int nt = 0; nt < 4; nt++)
        for (int r = 0; r < 4; r++) {
            int row = qb * 64 + wave * 16 + quad * 4 + r;
            o_ws[(size_t)(b * 1024 + row) * 1024 + h * 64 + nt * 16 + lm] = f2bf(oacc[nt][r]);
        }
}

// ---------------------------------------------------------------------------
extern "C" void kernel_launch(void* const* d_in, const int* in_sizes, int n_in,
                              void* d_out, int out_size, void* d_ws, size_t ws_size,
                              hipStream_t stream) {
    const float* x    = (const float*)d_in[0];   // fp32 per reference
    const int*   mask = (const int*)d_in[1];
    const float* wqkv = (const float*)d_in[2];
    const float* wout = (const float*)d_in[3];
    const float* bout = (const float*)d_in[4];

    float* out  = (float*)d_out;                    // [8192][1024] fp32
    float* attn = out + (size_t)8192 * 1024;        // [128][1024][1024] fp32

    // workspace layout (~92 MB). vt aliases xbf (xbf dead after gemm_qkv).
    char* ws = (char*)d_ws;
    u16* xbf   = (u16*)(ws);                        // 16,777,216 B
    u16* vt    = xbf;                               // reuse after gemm_qkv
    u16* qkv   = (u16*)(ws + 16777216);             // 50,331,648 B
    u16* o_ws  = (u16*)(ws + 67108864);             // 16,777,216 B
    u16* wqkvT = (u16*)(ws + 83886080);             //  6,291,456 B
    u16* woutT = (u16*)(ws + 90177536);             //  2,097,152 B

    cast_f32_bf16<<<dim3(8192), 256, 0, stream>>>(x, xbf, 8388608);
    transpose_f32_bf16<<<dim3(48, 16), 256, 0, stream>>>(wqkv, wqkvT, 1024, 3072);
    transpose_f32_bf16<<<dim3(16, 16), 256, 0, stream>>>(wout, woutT, 1024, 1024);
    gemm_bt<false, false><<<dim3(24, 64), 256, 0, stream>>>(xbf, wqkvT, nullptr, qkv, 8192, 3072, 1024);
    make_vt<<<dim3(16, 128), 256, 0, stream>>>(qkv, vt);
    attn_mfma<<<dim3(16, 128), 256, 0, stream>>>(qkv, vt, mask, attn, o_ws);
    gemm_bt<true, true><<<dim3(8, 64), 256, 0, stream>>>(o_ws, woutT, bout, out, 8192, 1024, 1024);
}